// Round 3
// baseline (1058.041 us; speedup 1.0000x reference)
//
#include <hip/hip_runtime.h>

// ---------------------------------------------------------------------------
// PrimitiveDecoder: 4-layer LSTM (NH=1024), T=101 steps, tiny head.
//
// Round-8: fully wave-autonomous dataflow. Key observation: each lane's dot
// consumes exactly the h-chunks at its own lane index (chunks {lane, 64+lane}
// of each 2KB slab). So instead of 2 staging waves polling into LDS + barrier
// + LDS handoff + single publisher wave, EVERY wave polls its own operand
// slices directly from the replica slabs and publishes its own unit pair:
//   - ZERO __syncthreads, ZERO LDS in the whole kernel
//   - critical cycle per layer-step: compute -> 8-lane replica scatter store
//     -> fabric visibility -> own-lane dwordx4 poll detect -> compute
//   - polls: 2x/4x global_load_dwordx4 issued back-to-back in ONE asm block
//     (single vmcnt(0) per round = 1 fabric RT per round; round-7 lesson:
//     no scalar-dword splitting, no pre-check sleeps)
//   - publish: lane r<8 stores the wave's packed h pair to replica r
//     (write-once slabs, NaN-sentinel detect; h=sigm*tanh is never NaN)
//   - wave 6 of group-0 blocks / group1-gb0 does the tiny head after its
//     publish (non-blocking try at lag 3, blocking drain at the end)
//   - __expf nonlinearity (validated round-7: absmax unchanged)
// ---------------------------------------------------------------------------

#define TT    101
#define NBLK  256
#define NTH   512
#define NREP  8
#define SLAB_U32 512                               // 1024 f16 per replica
#define HB16_BYTES (4 * TT * NREP * SLAB_U32 * 4)  // 6,615,040 B
#define OUT_PROBS 6464
#define OUT_SAMP  6666
#define SENT 0xFFFFFFFFu

typedef _Float16 h2 __attribute__((ext_vector_type(2)));

__device__ __forceinline__ h2 mkh2(float a, float b) {
    h2 r; r.x = (_Float16)a; r.y = (_Float16)b; return r;
}
__device__ __forceinline__ unsigned pack2(float a, float b) {
    return __builtin_bit_cast(unsigned, mkh2(a, b));
}
__device__ __forceinline__ h2 as_h2(unsigned u) { return __builtin_bit_cast(h2, u); }

#if __has_builtin(__builtin_amdgcn_fdot2)
__device__ __forceinline__ float fdot2(h2 a, h2 b, float c) {
    return __builtin_amdgcn_fdot2(a, b, c, false);
}
#else
__device__ __forceinline__ float fdot2(h2 a, h2 b, float c) {
    return fmaf((float)a.x, (float)b.x, fmaf((float)a.y, (float)b.y, c));
}
#endif

__device__ __forceinline__ void store4_bypass(unsigned* p, unsigned v) {
    asm volatile("global_store_dword %0, %1, off sc0 sc1" :: "v"(p), "v"(v) : "memory");
}

// Two 16B cache-bypass loads back-to-back, ONE vmcnt(0): 1 RT per round.
__device__ __forceinline__ void load32_bypass2(const uint4* p0, const uint4* p1,
                                               uint4& r0, uint4& r1) {
    asm volatile("global_load_dwordx4 %0, %2, off sc0 sc1\n\t"
                 "global_load_dwordx4 %1, %3, off sc0 sc1\n\t"
                 "s_waitcnt vmcnt(0)"
                 : "=&v"(r0), "=&v"(r1) : "v"(p0), "v"(p1) : "memory");
}

// Four 16B cache-bypass loads back-to-back, ONE vmcnt(0): 1 RT total.
__device__ __forceinline__ void load64_bypass4(const uint4* p0, const uint4* p1,
                                               const uint4* p2, const uint4* p3,
                                               uint4& r0, uint4& r1, uint4& r2, uint4& r3) {
    asm volatile("global_load_dwordx4 %0, %4, off sc0 sc1\n\t"
                 "global_load_dwordx4 %1, %5, off sc0 sc1\n\t"
                 "global_load_dwordx4 %2, %6, off sc0 sc1\n\t"
                 "global_load_dwordx4 %3, %7, off sc0 sc1\n\t"
                 "s_waitcnt vmcnt(0)"
                 : "=&v"(r0), "=&v"(r1), "=&v"(r2), "=&v"(r3)
                 : "v"(p0), "v"(p1), "v"(p2), "v"(p3) : "memory");
}

__device__ __forceinline__ bool stale(const uint4& u) {
    return (u.x == SENT) | (u.y == SENT) | (u.z == SENT) | (u.w == SENT);
}

// rocPRIM-style full-wave (64) sum via DPP; total broadcast via readlane(63).
__device__ __forceinline__ float wave_sum(float x) {
    int v;
    v = __builtin_amdgcn_update_dpp(0, __builtin_bit_cast(int, x), 0x111, 0xf, 0xf, false);
    x += __builtin_bit_cast(float, v);                                  // row_shr:1
    v = __builtin_amdgcn_update_dpp(0, __builtin_bit_cast(int, x), 0x112, 0xf, 0xf, false);
    x += __builtin_bit_cast(float, v);                                  // row_shr:2
    v = __builtin_amdgcn_update_dpp(0, __builtin_bit_cast(int, x), 0x114, 0xf, 0xe, false);
    x += __builtin_bit_cast(float, v);                                  // row_shr:4
    v = __builtin_amdgcn_update_dpp(0, __builtin_bit_cast(int, x), 0x118, 0xf, 0xc, false);
    x += __builtin_bit_cast(float, v);                                  // row_shr:8
    v = __builtin_amdgcn_update_dpp(0, __builtin_bit_cast(int, x), 0x142, 0xa, 0xf, false);
    x += __builtin_bit_cast(float, v);                                  // row_bcast:15
    v = __builtin_amdgcn_update_dpp(0, __builtin_bit_cast(int, x), 0x143, 0xc, 0xf, false);
    x += __builtin_bit_cast(float, v);                                  // row_bcast:31
    return __builtin_bit_cast(float, __builtin_amdgcn_readlane(__builtin_bit_cast(int, x), 63));
}

// fast transcendentals (v_exp_f32-based); validated round-7 (absmax equal).
__device__ __forceinline__ float sigm(float x)   { return 1.f / (1.f + __expf(-x)); }
__device__ __forceinline__ float tanh_f(float x) { return 1.f - 2.f / (1.f + __expf(x + x)); }

// ---------------------------------------------------------------------------
__global__ __launch_bounds__(NTH, 2) void lstm_kernel(
    const float* __restrict__ z,
    const float* __restrict__ Wih, const float* __restrict__ Whh,
    const float* __restrict__ bih, const float* __restrict__ bhh,
    const float* __restrict__ Ws,  const float* __restrict__ bs,
    const float* __restrict__ Wp,  const float* __restrict__ bp,
    unsigned* __restrict__ hb16, float* __restrict__ out)
{
    const int tid  = threadIdx.x;
    const int wv   = tid >> 6;
    const int lane = tid & 63;
    const int l    = blockIdx.x >> 6;          // layer / group
    const int gb   = blockIdx.x & 63;          // block-in-group
    const int uA   = (gb << 4) + (wv << 1);    // wave's first unit

    // ---- weights -> registers (fp32 -> f16), chunk-aligned layout --------
    // lane's dot coverage: chunks {lane, 64+lane} of each operand vector
    //   k0-3:  Whh cols 8*lane..+7    k4-7:  Whh cols 512+8*lane..+7
    //   k8-11: Wih cols 8*lane..+7    k12-15:Wih cols 512+8*lane..+7
    h2 w[8][16];
    #pragma unroll
    for (int r = 0; r < 8; ++r) {
        const int u = uA + (r >> 2);
        const int g = r & 3;
        const size_t row = ((size_t)((l << 12) + (g << 10) + u)) << 10;
        const float4* pa = (const float4*)(Whh + row + (lane << 3));
        const float4* pb = (const float4*)(Whh + row + 512 + (lane << 3));
        const float4* pc = (const float4*)(Wih + row + (lane << 3));
        const float4* pd = (const float4*)(Wih + row + 512 + (lane << 3));
        float4 f;
        f = pa[0]; w[r][0]  = mkh2(f.x, f.y); w[r][1]  = mkh2(f.z, f.w);
        f = pa[1]; w[r][2]  = mkh2(f.x, f.y); w[r][3]  = mkh2(f.z, f.w);
        f = pb[0]; w[r][4]  = mkh2(f.x, f.y); w[r][5]  = mkh2(f.z, f.w);
        f = pb[1]; w[r][6]  = mkh2(f.x, f.y); w[r][7]  = mkh2(f.z, f.w);
        f = pc[0]; w[r][8]  = mkh2(f.x, f.y); w[r][9]  = mkh2(f.z, f.w);
        f = pc[1]; w[r][10] = mkh2(f.x, f.y); w[r][11] = mkh2(f.z, f.w);
        f = pd[0]; w[r][12] = mkh2(f.x, f.y); w[r][13] = mkh2(f.z, f.w);
        f = pd[1]; w[r][14] = mkh2(f.x, f.y); w[r][15] = mkh2(f.z, f.w);
    }

    float bA[4], bB[4];
    #pragma unroll
    for (int g = 0; g < 4; ++g) {
        const int iA = (l << 12) + (g << 10) + uA;
        bA[g] = bih[iA] + bhh[iA];
        bB[g] = bih[iA + 1] + bhh[iA + 1];
    }

    // ---- head role (wave 6) ----------------------------------------------
    const bool role_states = (l == 0 && wv == 6);
    const bool role_probs  = (l == 1 && gb == 0 && wv == 6);
    float hw0[16], hw1[16], hb0 = 0.f, hb1 = 0.f;
    if (role_states) {
        #pragma unroll
        for (int k = 0; k < 16; ++k) hw0[k] = Ws[(gb << 10) + (lane << 4) + k];
        hb0 = bs[gb];
    } else if (role_probs) {
        #pragma unroll
        for (int k = 0; k < 16; ++k) {
            hw0[k] = Wp[(lane << 4) + k];
            hw1[k] = Wp[1024 + (lane << 4) + k];
        }
        hb0 = bp[0]; hb1 = bp[1];
    }
    int th = 0;

    float cstA = 0.f, cstB = 0.f;

    #pragma unroll 1
    for (int t = 0; t < TT; ++t) {
        const int rep = (gb + wv) & (NREP - 1);
        const bool needA = (t > 0);                // part1: h_l(t-1)
        const bool needB = (l > 0);                // part2: h_{l-1}(t)
        uint4 A1 = {}, A2 = {}, B1 = {}, B2 = {};

        // ---- acquire operands: own-lane slices, 1-RT poll rounds ----
        if (needA && needB) {
            const uint4* pa = (const uint4*)(hb16 + (size_t)((l * TT + t - 1) * NREP + rep) * SLAB_U32);
            const uint4* pb = (const uint4*)(hb16 + (size_t)(((l - 1) * TT + t) * NREP + rep) * SLAB_U32);
            load64_bypass4(pa + lane, pa + 64 + lane, pb + lane, pb + 64 + lane,
                           A1, A2, B1, B2);
            while (stale(A1) | stale(A2)) {
                __builtin_amdgcn_s_sleep(1);
                load32_bypass2(pa + lane, pa + 64 + lane, A1, A2);
            }
            while (stale(B1) | stale(B2)) {
                __builtin_amdgcn_s_sleep(1);
                load32_bypass2(pb + lane, pb + 64 + lane, B1, B2);
            }
        } else if (needA) {                        // l==0, t>0 (input is zeros)
            const uint4* pa = (const uint4*)(hb16 + (size_t)((l * TT + t - 1) * NREP + rep) * SLAB_U32);
            load32_bypass2(pa + lane, pa + 64 + lane, A1, A2);
            while (stale(A1) | stale(A2)) {
                __builtin_amdgcn_s_sleep(1);
                load32_bypass2(pa + lane, pa + 64 + lane, A1, A2);
            }
        } else if (needB) {                        // l>0, t==0
            const uint4* pb = (const uint4*)(hb16 + (size_t)(((l - 1) * TT) * NREP + rep) * SLAB_U32);
            load32_bypass2(pb + lane, pb + 64 + lane, B1, B2);
            while (stale(B1) | stale(B2)) {
                __builtin_amdgcn_s_sleep(1);
                load32_bypass2(pb + lane, pb + 64 + lane, B1, B2);
            }
        }
        const bool fullB = needB || (t == 0);      // l==0,t==0: B = z
        if (l == 0 && t == 0) {
            const float4 f0 = *(const float4*)(z + (lane << 3));
            const float4 f1 = *(const float4*)(z + (lane << 3) + 4);
            const float4 f2 = *(const float4*)(z + 512 + (lane << 3));
            const float4 f3 = *(const float4*)(z + 512 + (lane << 3) + 4);
            B1 = make_uint4(pack2(f0.x, f0.y), pack2(f0.z, f0.w),
                            pack2(f1.x, f1.y), pack2(f1.z, f1.w));
            B2 = make_uint4(pack2(f2.x, f2.y), pack2(f2.z, f2.w),
                            pack2(f3.x, f3.y), pack2(f3.z, f3.w));
        }

        // ---- dot: 8 gate rows per wave over own slices ----
        float acc[8] = {0.f, 0.f, 0.f, 0.f, 0.f, 0.f, 0.f, 0.f};
        if (needA) {
            const unsigned a8[8] = {A1.x, A1.y, A1.z, A1.w, A2.x, A2.y, A2.z, A2.w};
            #pragma unroll
            for (int k = 0; k < 8; ++k) {
                const h2 v2 = as_h2(a8[k]);
                #pragma unroll
                for (int r = 0; r < 8; ++r) acc[r] = fdot2(w[r][k], v2, acc[r]);
            }
        }
        if (fullB) {
            const unsigned b8[8] = {B1.x, B1.y, B1.z, B1.w, B2.x, B2.y, B2.z, B2.w};
            #pragma unroll
            for (int k = 0; k < 8; ++k) {
                const h2 v2 = as_h2(b8[k]);
                #pragma unroll
                for (int r = 0; r < 8; ++r) acc[r] = fdot2(w[r][8 + k], v2, acc[r]);
            }
        }

        // ---- DPP reduce -> uniform gate sums ----
        float tot[8];
        #pragma unroll
        for (int r = 0; r < 8; ++r) tot[r] = wave_sum(acc[r]);

        // ---- uniform nonlinearity on all lanes ----
        cstA = fmaf(sigm(tot[1] + bA[1]), cstA, sigm(tot[0] + bA[0]) * tanh_f(tot[2] + bA[2]));
        cstB = fmaf(sigm(tot[5] + bB[1]), cstB, sigm(tot[4] + bB[0]) * tanh_f(tot[6] + bB[2]));
        const float hA = sigm(tot[3] + bA[3]) * tanh_f(cstA);
        const float hB = sigm(tot[7] + bB[3]) * tanh_f(cstB);

        // ---- publish: lane r<8 stores the wave's packed pair to replica r ----
        const unsigned val = pack2(hA, hB);
        if (lane < NREP) {
            unsigned* addr = hb16 + (size_t)((l * TT + t) * NREP) * SLAB_U32
                           + (size_t)lane * SLAB_U32 + (gb << 3) + wv;
            store4_bypass(addr, val);
        }

        // ---- head: non-blocking single-shot try at lag 3 (1 RT) ----
        if ((role_states || role_probs) && th < TT && th <= t - 3) {
            const int hrep = (gb + th) & (NREP - 1);
            const uint4* slab3 = (const uint4*)(hb16 + (size_t)((3 * TT + th) * NREP + hrep) * SLAB_U32);
            uint4 r0, r1;
            load32_bypass2(slab3 + (lane << 1), slab3 + (lane << 1) + 1, r0, r1);
            const bool ok = !(stale(r0) | stale(r1));
            if (__ballot(ok) == ~0ull) {
                const unsigned u8[8] = {r0.x, r0.y, r0.z, r0.w, r1.x, r1.y, r1.z, r1.w};
                if (role_states) {
                    float a = 0.f;
                    #pragma unroll
                    for (int j = 0; j < 8; ++j) {
                        const h2 p = as_h2(u8[j]);
                        a = fmaf(hw0[2 * j], (float)p.x, a);
                        a = fmaf(hw0[2 * j + 1], (float)p.y, a);
                    }
                    const float tots = wave_sum(a);
                    if (lane == 0) out[th * 64 + gb] = tots + hb0;
                } else {
                    float a0 = 0.f, a1 = 0.f;
                    #pragma unroll
                    for (int j = 0; j < 8; ++j) {
                        const h2 p = as_h2(u8[j]);
                        a0 = fmaf(hw0[2 * j], (float)p.x, a0); a0 = fmaf(hw0[2 * j + 1], (float)p.y, a0);
                        a1 = fmaf(hw1[2 * j], (float)p.x, a1); a1 = fmaf(hw1[2 * j + 1], (float)p.y, a1);
                    }
                    const float t0 = wave_sum(a0), t1 = wave_sum(a1);
                    if (lane == 0) {
                        float p0, p1;
                        if (th == TT - 1) { p0 = 0.f; p1 = 1.f; }
                        else {
                            const float l0 = t0 + hb0 + 1.0f;   // P_BIAS
                            const float l1 = t1 + hb1;
                            const float m  = fmaxf(l0, l1);
                            const float e0 = expf(l0 - m), e1 = expf(l1 - m);
                            const float inv = 1.f / (e0 + e1);
                            p0 = e0 * inv; p1 = e1 * inv;
                        }
                        out[OUT_PROBS + 2 * th]     = p0;
                        out[OUT_PROBS + 2 * th + 1] = p1;
                        out[OUT_SAMP + th] = (th == TT - 1) ? 1.0f : 0.0f;
                    }
                }
                ++th;
            }
        }
    }

    // ---- head drain (blocking) ----
    if (role_states || role_probs) {
        while (th < TT) {
            const int hrep = (gb + th) & (NREP - 1);
            const uint4* slab3 = (const uint4*)(hb16 + (size_t)((3 * TT + th) * NREP + hrep) * SLAB_U32);
            uint4 r0, r1;
            for (;;) {
                load32_bypass2(slab3 + (lane << 1), slab3 + (lane << 1) + 1, r0, r1);
                if (!(stale(r0) | stale(r1))) break;
                __builtin_amdgcn_s_sleep(1);
            }
            const unsigned u8[8] = {r0.x, r0.y, r0.z, r0.w, r1.x, r1.y, r1.z, r1.w};
            if (role_states) {
                float a = 0.f;
                #pragma unroll
                for (int j = 0; j < 8; ++j) {
                    const h2 p = as_h2(u8[j]);
                    a = fmaf(hw0[2 * j], (float)p.x, a);
                    a = fmaf(hw0[2 * j + 1], (float)p.y, a);
                }
                const float tots = wave_sum(a);
                if (lane == 0) out[th * 64 + gb] = tots + hb0;
            } else {
                float a0 = 0.f, a1 = 0.f;
                #pragma unroll
                for (int j = 0; j < 8; ++j) {
                    const h2 p = as_h2(u8[j]);
                    a0 = fmaf(hw0[2 * j], (float)p.x, a0); a0 = fmaf(hw0[2 * j + 1], (float)p.y, a0);
                    a1 = fmaf(hw1[2 * j], (float)p.x, a1); a1 = fmaf(hw1[2 * j + 1], (float)p.y, a1);
                }
                const float t0 = wave_sum(a0), t1 = wave_sum(a1);
                if (lane == 0) {
                    float p0, p1;
                    if (th == TT - 1) { p0 = 0.f; p1 = 1.f; }
                    else {
                        const float l0 = t0 + hb0 + 1.0f;
                        const float l1 = t1 + hb1;
                        const float m  = fmaxf(l0, l1);
                        const float e0 = expf(l0 - m), e1 = expf(l1 - m);
                        const float inv = 1.f / (e0 + e1);
                        p0 = e0 * inv; p1 = e1 * inv;
                    }
                    out[OUT_PROBS + 2 * th]     = p0;
                    out[OUT_PROBS + 2 * th + 1] = p1;
                    out[OUT_SAMP + th] = (th == TT - 1) ? 1.0f : 0.0f;
                }
            }
            ++th;
        }
    }
}

// ---------------------------------------------------------------------------
extern "C" void kernel_launch(void* const* d_in, const int* in_sizes, int n_in,
                              void* d_out, int out_size, void* d_ws, size_t ws_size,
                              hipStream_t stream)
{
    const float* z   = (const float*)d_in[0];
    const float* Wih = (const float*)d_in[1];
    const float* Whh = (const float*)d_in[2];
    const float* bih = (const float*)d_in[3];
    const float* bhh = (const float*)d_in[4];
    const float* Ws  = (const float*)d_in[5];
    const float* bs  = (const float*)d_in[6];
    const float* Wp  = (const float*)d_in[7];
    const float* bp  = (const float*)d_in[8];
    float* out = (float*)d_out;

    unsigned* hb16 = (unsigned*)d_ws;

    // sentinel-init replicas (ws is re-poisoned before every timed call)
    hipMemsetAsync(hb16, 0xFF, HB16_BYTES, stream);
    lstm_kernel<<<NBLK, NTH, 0, stream>>>(z, Wih, Whh, bih, bhh,
                                          Ws, bs, Wp, bp, hb16, out);
}

// Round 4
// 644.613 us; speedup vs baseline: 1.6414x; 1.6414x over previous
//
#include <hip/hip_runtime.h>

// ---------------------------------------------------------------------------
// PrimitiveDecoder: 4-layer LSTM (NH=1024), T=101 steps, tiny head.
//
// Round-9 = round-5 structure (measured 406us dispatch, best so far) +
// atomic release-counter poll gating + two validated micro-fixes.
//
// Round-5 recap: 4 groups x 64 blocks (grid 256 = 1/CU), 512 thr.
//  loop { waves 0-3 poll-stage h chunks into LDS; barrier1;
//         all waves: 4x ds_read_b128 dot + DPP wave-reduce + uniform nonlin;
//         lane0 -> hout[wv]; barrier2;
//         wave7: ONE 64-lane scatter store (8 replicas x 8 dwords);
//         wave6: head try at lag 3 }
//
// Round-9 additions (lessons: R7 sleep-before-check/scalar-split polls cost
// +66us; R8 8x poll traffic cost +478us -> poll TRAFFIC drives the hop):
//  1. Release counter per (l,t): publisher lane0 atomicAdd AFTER its data
//     stores (no vmcnt wait -- counter lands ~parallel with data; nothing
//     new on producer critical path). Staging waves: one speculative 16B
//     read; if stale, spin on the 4B counter (one line/round, ~250x less
//     retry traffic than re-reading 1KB/wave), then re-read. Sentinels stay
//     authoritative (backstop loop covers counter-outruns-data), so the
//     sync protocol's correctness is exactly R5's.
//     Counters sit past the slab region, guarded by ws_size (else nullptr
//     -> pure R5 behavior).
//  2. __expf-based sigmoid/tanh (validated R7/R8: absmax unchanged).
//  3. Head: both 16B loads in one asm block, single vmcnt(0) -> 1 RT.
// ---------------------------------------------------------------------------

#define TT    101
#define NBLK  256
#define NTH   512
#define NREP  8
#define SLAB_U32 512                               // 1024 f16 per replica
#define HB16_U32  (4 * TT * NREP * SLAB_U32)       // slab region dwords
#define HB16_BYTES (HB16_U32 * 4)                  // 6,615,040 B
#define CNT_BYTES (4 * TT * 4)                     // 1,616 B
#define OUT_PROBS 6464
#define OUT_SAMP  6666
#define SENT 0xFFFFFFFFu

typedef _Float16 h2 __attribute__((ext_vector_type(2)));

__device__ __forceinline__ h2 mkh2(float a, float b) {
    h2 r; r.x = (_Float16)a; r.y = (_Float16)b; return r;
}
__device__ __forceinline__ unsigned pack2(float a, float b) {
    return __builtin_bit_cast(unsigned, mkh2(a, b));
}
__device__ __forceinline__ h2 as_h2(unsigned u) { return __builtin_bit_cast(h2, u); }

#if __has_builtin(__builtin_amdgcn_fdot2)
__device__ __forceinline__ float fdot2(h2 a, h2 b, float c) {
    return __builtin_amdgcn_fdot2(a, b, c, false);
}
#else
__device__ __forceinline__ float fdot2(h2 a, h2 b, float c) {
    return fmaf((float)a.x, (float)b.x, fmaf((float)a.y, (float)b.y, c));
}
#endif

// 16B cache-bypass load (coherent); waitcnt inside so result regs valid.
__device__ __forceinline__ uint4 load16_bypass(const uint4* p) {
    uint4 r;
    asm volatile("global_load_dwordx4 %0, %1, off sc0 sc1\n\ts_waitcnt vmcnt(0)"
                 : "=v"(r) : "v"(p) : "memory");
    return r;
}
// 4B cache-bypass load (counter poll: one line request per wave-round).
__device__ __forceinline__ unsigned load4_bypass(const unsigned* p) {
    unsigned r;
    asm volatile("global_load_dword %0, %1, off sc0 sc1\n\ts_waitcnt vmcnt(0)"
                 : "=v"(r) : "v"(p) : "memory");
    return r;
}
__device__ __forceinline__ void store4_bypass(unsigned* p, unsigned v) {
    asm volatile("global_store_dword %0, %1, off sc0 sc1" :: "v"(p), "v"(v) : "memory");
}
// Two 16B cache-bypass loads back-to-back, ONE vmcnt(0): 1 RT not 2.
__device__ __forceinline__ void load32_bypass2(const uint4* p0, const uint4* p1,
                                               uint4& r0, uint4& r1) {
    asm volatile("global_load_dwordx4 %0, %2, off sc0 sc1\n\t"
                 "global_load_dwordx4 %1, %3, off sc0 sc1\n\t"
                 "s_waitcnt vmcnt(0)"
                 : "=&v"(r0), "=&v"(r1) : "v"(p0), "v"(p1) : "memory");
}

__device__ __forceinline__ bool stale(const uint4& u) {
    return (u.x == SENT) | (u.y == SENT) | (u.z == SENT) | (u.w == SENT);
}

// Gated poll: speculative read; on miss spin on 4B release counter, then
// re-read with sentinel backstop (counter may slightly outrun data stores).
__device__ __forceinline__ uint4 poll16_gated(const uint4* p, const unsigned* ca) {
    uint4 r = load16_bypass(p);
    if (stale(r)) {
        if (ca) {
            while (load4_bypass(ca) < 64u) __builtin_amdgcn_s_sleep(2);
        }
        r = load16_bypass(p);
        while (stale(r)) {
            __builtin_amdgcn_s_sleep(1);
            r = load16_bypass(p);
        }
    }
    return r;
}

// rocPRIM-style full-wave (64) sum via DPP; total broadcast via readlane(63).
__device__ __forceinline__ float wave_sum(float x) {
    int v;
    v = __builtin_amdgcn_update_dpp(0, __builtin_bit_cast(int, x), 0x111, 0xf, 0xf, false);
    x += __builtin_bit_cast(float, v);                                  // row_shr:1
    v = __builtin_amdgcn_update_dpp(0, __builtin_bit_cast(int, x), 0x112, 0xf, 0xf, false);
    x += __builtin_bit_cast(float, v);                                  // row_shr:2
    v = __builtin_amdgcn_update_dpp(0, __builtin_bit_cast(int, x), 0x114, 0xf, 0xe, false);
    x += __builtin_bit_cast(float, v);                                  // row_shr:4
    v = __builtin_amdgcn_update_dpp(0, __builtin_bit_cast(int, x), 0x118, 0xf, 0xc, false);
    x += __builtin_bit_cast(float, v);                                  // row_shr:8
    v = __builtin_amdgcn_update_dpp(0, __builtin_bit_cast(int, x), 0x142, 0xa, 0xf, false);
    x += __builtin_bit_cast(float, v);                                  // row_bcast:15
    v = __builtin_amdgcn_update_dpp(0, __builtin_bit_cast(int, x), 0x143, 0xc, 0xf, false);
    x += __builtin_bit_cast(float, v);                                  // row_bcast:31
    return __builtin_bit_cast(float, __builtin_amdgcn_readlane(__builtin_bit_cast(int, x), 63));
}

// fast transcendentals (v_exp_f32-based); validated R7/R8: absmax unchanged.
__device__ __forceinline__ float sigm(float x)   { return 1.f / (1.f + __expf(-x)); }
__device__ __forceinline__ float tanh_f(float x) { return 1.f - 2.f / (1.f + __expf(x + x)); }

// ---------------------------------------------------------------------------
__global__ __launch_bounds__(NTH, 2) void lstm_kernel(
    const float* __restrict__ z,
    const float* __restrict__ Wih, const float* __restrict__ Whh,
    const float* __restrict__ bih, const float* __restrict__ bhh,
    const float* __restrict__ Ws,  const float* __restrict__ bs,
    const float* __restrict__ Wp,  const float* __restrict__ bp,
    unsigned* __restrict__ hb16, unsigned* __restrict__ cnt,
    float* __restrict__ out)
{
    const int tid  = threadIdx.x;
    const int wv   = tid >> 6;
    const int lane = tid & 63;
    const int l    = blockIdx.x >> 6;          // layer / group
    const int gb   = blockIdx.x & 63;          // block-in-group
    const int uA   = (gb << 4) + (wv << 1);    // wave's first unit

    __shared__ __align__(16) uint4 vh4[256];   // 256 chunks: [part1 128 | part2 128]
    __shared__ unsigned hout[8];               // packed h pair per wave

    // ---- weights -> registers (fp32 -> f16), chunk-aligned layout --------
    // lane's dot coverage: chunks {lane, 64+lane} of each part
    //   k0-3:  Whh cols 8*lane   .. +7      k4-7:  Whh cols 512+8*lane .. +7
    //   k8-11: Wih cols 8*lane   .. +7      k12-15:Wih cols 512+8*lane .. +7
    h2 w[8][16];
    #pragma unroll
    for (int r = 0; r < 8; ++r) {
        const int u = uA + (r >> 2);
        const int g = r & 3;
        const size_t row = ((size_t)((l << 12) + (g << 10) + u)) << 10;
        const float4* pa = (const float4*)(Whh + row + (lane << 3));
        const float4* pb = (const float4*)(Whh + row + 512 + (lane << 3));
        const float4* pc = (const float4*)(Wih + row + (lane << 3));
        const float4* pd = (const float4*)(Wih + row + 512 + (lane << 3));
        float4 f;
        f = pa[0]; w[r][0]  = mkh2(f.x, f.y); w[r][1]  = mkh2(f.z, f.w);
        f = pa[1]; w[r][2]  = mkh2(f.x, f.y); w[r][3]  = mkh2(f.z, f.w);
        f = pb[0]; w[r][4]  = mkh2(f.x, f.y); w[r][5]  = mkh2(f.z, f.w);
        f = pb[1]; w[r][6]  = mkh2(f.x, f.y); w[r][7]  = mkh2(f.z, f.w);
        f = pc[0]; w[r][8]  = mkh2(f.x, f.y); w[r][9]  = mkh2(f.z, f.w);
        f = pc[1]; w[r][10] = mkh2(f.x, f.y); w[r][11] = mkh2(f.z, f.w);
        f = pd[0]; w[r][12] = mkh2(f.x, f.y); w[r][13] = mkh2(f.z, f.w);
        f = pd[1]; w[r][14] = mkh2(f.x, f.y); w[r][15] = mkh2(f.z, f.w);
    }

    float bA[4], bB[4];
    #pragma unroll
    for (int g = 0; g < 4; ++g) {
        const int iA = (l << 12) + (g << 10) + uA;
        bA[g] = bih[iA] + bhh[iA];
        bB[g] = bih[iA + 1] + bhh[iA + 1];
    }

    // ---- head role (wave 6) ----------------------------------------------
    const bool role_states = (l == 0 && wv == 6);
    const bool role_probs  = (l == 1 && gb == 0 && wv == 6);
    float hw0[16], hw1[16], hb0 = 0.f, hb1 = 0.f;
    if (role_states) {
        #pragma unroll
        for (int k = 0; k < 16; ++k) hw0[k] = Ws[(gb << 10) + (lane << 4) + k];
        hb0 = bs[gb];
    } else if (role_probs) {
        #pragma unroll
        for (int k = 0; k < 16; ++k) {
            hw0[k] = Wp[(lane << 4) + k];
            hw1[k] = Wp[1024 + (lane << 4) + k];
        }
        hb0 = bp[0]; hb1 = bp[1];
    }
    int th = 0;

    float cstA = 0.f, cstB = 0.f;

    #pragma unroll 1
    for (int t = 0; t < TT; ++t) {
        const bool full = (l > 0) || (t == 0);
        const int rep = (gb + wv) & (NREP - 1);

        // ---- staging (waves 0-3; they never global-store) ----
        if (wv < 2) {                              // part1: h_l(t-1)
            const int c = (wv << 6) + lane;
            if (t == 0) vh4[c] = make_uint4(0, 0, 0, 0);
            else {
                const uint4* slab = (const uint4*)(hb16 + (size_t)((l * TT + t - 1) * NREP + rep) * SLAB_U32);
                const unsigned* ca = cnt ? cnt + (l * TT + t - 1) : nullptr;
                vh4[c] = poll16_gated(slab + c, ca);
            }
        } else if (wv < 4) {                       // part2: h_{l-1}(t) or z
            const int c = ((wv - 2) << 6) + lane;
            if (l > 0) {
                const uint4* slab = (const uint4*)(hb16 + (size_t)(((l - 1) * TT + t) * NREP + rep) * SLAB_U32);
                const unsigned* ca = cnt ? cnt + ((l - 1) * TT + t) : nullptr;
                vh4[128 + c] = poll16_gated(slab + c, ca);
            } else if (t == 0) {
                const float4 f0 = *(const float4*)(z + (c << 3));
                const float4 f1 = *(const float4*)(z + (c << 3) + 4);
                vh4[128 + c] = make_uint4(pack2(f0.x, f0.y), pack2(f0.z, f0.w),
                                          pack2(f1.x, f1.y), pack2(f1.z, f1.w));
            }
        }
        __syncthreads();                           // barrier1

        // ---- dot: 8 gate rows per wave, 4x ds_read_b128 ----
        float acc[8] = {0.f, 0.f, 0.f, 0.f, 0.f, 0.f, 0.f, 0.f};
        {
            const uint4 A1 = vh4[lane];
            const uint4 A2 = vh4[64 + lane];
            const unsigned a8[8] = {A1.x, A1.y, A1.z, A1.w, A2.x, A2.y, A2.z, A2.w};
            #pragma unroll
            for (int k = 0; k < 8; ++k) {
                const h2 v2 = as_h2(a8[k]);
                #pragma unroll
                for (int r = 0; r < 8; ++r) acc[r] = fdot2(w[r][k], v2, acc[r]);
            }
            if (full) {
                const uint4 B1 = vh4[128 + lane];
                const uint4 B2 = vh4[192 + lane];
                const unsigned b8[8] = {B1.x, B1.y, B1.z, B1.w, B2.x, B2.y, B2.z, B2.w};
                #pragma unroll
                for (int k = 0; k < 8; ++k) {
                    const h2 v2 = as_h2(b8[k]);
                    #pragma unroll
                    for (int r = 0; r < 8; ++r) acc[r] = fdot2(w[r][8 + k], v2, acc[r]);
                }
            }
        }

        // ---- DPP reduce (VALU pipe) -> uniform gate sums ----
        float tot[8];
        #pragma unroll
        for (int r = 0; r < 8; ++r) tot[r] = wave_sum(acc[r]);

        // ---- uniform nonlinearity on all lanes ----
        cstA = fmaf(sigm(tot[1] + bA[1]), cstA, sigm(tot[0] + bA[0]) * tanh_f(tot[2] + bA[2]));
        cstB = fmaf(sigm(tot[5] + bB[1]), cstB, sigm(tot[4] + bB[0]) * tanh_f(tot[6] + bB[2]));
        const float hA = sigm(tot[3] + bA[3]) * tanh_f(cstA);
        const float hB = sigm(tot[7] + bB[3]) * tanh_f(cstB);
        if (lane == 0) hout[wv] = pack2(hA, hB);
        __syncthreads();                           // barrier2

        if (wv == 7) {
            // ---- publish: ONE 64-lane scatter store (8 replicas x 8 dwords);
            // then lane0 bumps the release counter (no vmcnt -- it lands
            // ~parallel with the data; consumers' sentinel backstop covers
            // any counter-outruns-data window). Acks drain at next barrier1.
            const unsigned val = hout[lane & 7];
            unsigned* addr = hb16 + (size_t)(l * TT + t) * NREP * SLAB_U32
                           + (size_t)(lane >> 3) * SLAB_U32 + (gb << 3) + (lane & 7);
            store4_bypass(addr, val);
            if (lane == 0 && cnt) atomicAdd(cnt + (l * TT + t), 1u);
        } else if ((role_states || role_probs) && th < TT && th <= t - 3) {
            // ---- head: non-blocking single-shot try at lag 3 (1 RT) ----
            const int hrep = (gb + th) & (NREP - 1);
            const uint4* slab3 = (const uint4*)(hb16 + (size_t)((3 * TT + th) * NREP + hrep) * SLAB_U32);
            uint4 r0, r1;
            load32_bypass2(slab3 + (lane << 1), slab3 + (lane << 1) + 1, r0, r1);
            const bool ok = !(stale(r0) | stale(r1));
            if (__ballot(ok) == ~0ull) {
                const unsigned u8[8] = {r0.x, r0.y, r0.z, r0.w, r1.x, r1.y, r1.z, r1.w};
                if (role_states) {
                    float a = 0.f;
                    #pragma unroll
                    for (int j = 0; j < 8; ++j) {
                        const h2 p = as_h2(u8[j]);
                        a = fmaf(hw0[2 * j], (float)p.x, a);
                        a = fmaf(hw0[2 * j + 1], (float)p.y, a);
                    }
                    const float tots = wave_sum(a);
                    if (lane == 0) out[th * 64 + gb] = tots + hb0;
                } else {
                    float a0 = 0.f, a1 = 0.f;
                    #pragma unroll
                    for (int j = 0; j < 8; ++j) {
                        const h2 p = as_h2(u8[j]);
                        a0 = fmaf(hw0[2 * j], (float)p.x, a0); a0 = fmaf(hw0[2 * j + 1], (float)p.y, a0);
                        a1 = fmaf(hw1[2 * j], (float)p.x, a1); a1 = fmaf(hw1[2 * j + 1], (float)p.y, a1);
                    }
                    const float t0 = wave_sum(a0), t1 = wave_sum(a1);
                    if (lane == 0) {
                        float p0, p1;
                        if (th == TT - 1) { p0 = 0.f; p1 = 1.f; }
                        else {
                            const float l0 = t0 + hb0 + 1.0f;   // P_BIAS
                            const float l1 = t1 + hb1;
                            const float m  = fmaxf(l0, l1);
                            const float e0 = expf(l0 - m), e1 = expf(l1 - m);
                            const float inv = 1.f / (e0 + e1);
                            p0 = e0 * inv; p1 = e1 * inv;
                        }
                        out[OUT_PROBS + 2 * th]     = p0;
                        out[OUT_PROBS + 2 * th + 1] = p1;
                        out[OUT_SAMP + th] = (th == TT - 1) ? 1.0f : 0.0f;
                    }
                }
                ++th;
            }
        }
    }

    // ---- head drain (blocking, counter-gated) ----
    if (role_states || role_probs) {
        while (th < TT) {
            const int hrep = (gb + th) & (NREP - 1);
            const uint4* slab3 = (const uint4*)(hb16 + (size_t)((3 * TT + th) * NREP + hrep) * SLAB_U32);
            if (cnt) {
                const unsigned* ca = cnt + (3 * TT + th);
                while (load4_bypass(ca) < 64u) __builtin_amdgcn_s_sleep(2);
            }
            uint4 r0, r1;
            for (;;) {
                load32_bypass2(slab3 + (lane << 1), slab3 + (lane << 1) + 1, r0, r1);
                if (!(stale(r0) | stale(r1))) break;
                __builtin_amdgcn_s_sleep(1);
            }
            const unsigned u8[8] = {r0.x, r0.y, r0.z, r0.w, r1.x, r1.y, r1.z, r1.w};
            if (role_states) {
                float a = 0.f;
                #pragma unroll
                for (int j = 0; j < 8; ++j) {
                    const h2 p = as_h2(u8[j]);
                    a = fmaf(hw0[2 * j], (float)p.x, a);
                    a = fmaf(hw0[2 * j + 1], (float)p.y, a);
                }
                const float tots = wave_sum(a);
                if (lane == 0) out[th * 64 + gb] = tots + hb0;
            } else {
                float a0 = 0.f, a1 = 0.f;
                #pragma unroll
                for (int j = 0; j < 8; ++j) {
                    const h2 p = as_h2(u8[j]);
                    a0 = fmaf(hw0[2 * j], (float)p.x, a0); a0 = fmaf(hw0[2 * j + 1], (float)p.y, a0);
                    a1 = fmaf(hw1[2 * j], (float)p.x, a1); a1 = fmaf(hw1[2 * j + 1], (float)p.y, a1);
                }
                const float t0 = wave_sum(a0), t1 = wave_sum(a1);
                if (lane == 0) {
                    float p0, p1;
                    if (th == TT - 1) { p0 = 0.f; p1 = 1.f; }
                    else {
                        const float l0 = t0 + hb0 + 1.0f;
                        const float l1 = t1 + hb1;
                        const float m  = fmaxf(l0, l1);
                        const float e0 = expf(l0 - m), e1 = expf(l1 - m);
                        const float inv = 1.f / (e0 + e1);
                        p0 = e0 * inv; p1 = e1 * inv;
                    }
                    out[OUT_PROBS + 2 * th]     = p0;
                    out[OUT_PROBS + 2 * th + 1] = p1;
                    out[OUT_SAMP + th] = (th == TT - 1) ? 1.0f : 0.0f;
                }
            }
            ++th;
        }
    }
}

// ---------------------------------------------------------------------------
extern "C" void kernel_launch(void* const* d_in, const int* in_sizes, int n_in,
                              void* d_out, int out_size, void* d_ws, size_t ws_size,
                              hipStream_t stream)
{
    const float* z   = (const float*)d_in[0];
    const float* Wih = (const float*)d_in[1];
    const float* Whh = (const float*)d_in[2];
    const float* bih = (const float*)d_in[3];
    const float* bhh = (const float*)d_in[4];
    const float* Ws  = (const float*)d_in[5];
    const float* bs  = (const float*)d_in[6];
    const float* Wp  = (const float*)d_in[7];
    const float* bp  = (const float*)d_in[8];
    float* out = (float*)d_out;

    unsigned* hb16 = (unsigned*)d_ws;
    unsigned* cnt  = nullptr;
    if (ws_size >= (size_t)HB16_BYTES + CNT_BYTES) {
        cnt = hb16 + HB16_U32;
        hipMemsetAsync(cnt, 0, CNT_BYTES, stream);     // release counters = 0
    }
    // sentinel-init replicas (ws is re-poisoned before every timed call)
    hipMemsetAsync(hb16, 0xFF, HB16_BYTES, stream);
    lstm_kernel<<<NBLK, NTH, 0, stream>>>(z, Wih, Whh, bih, bhh,
                                          Ws, bs, Wp, bp, hb16, cnt, out);
}

// Round 5
// 463.525 us; speedup vs baseline: 2.2826x; 1.3907x over previous
//
#include <hip/hip_runtime.h>

// ---------------------------------------------------------------------------
// PrimitiveDecoder: 4-layer LSTM (NH=1024), T=101 steps, tiny head.
//
// Round-10 = EXACT round-5 structure (measured best: 406us dispatch) with
// three strictly-safe deltas. The R5 sync protocol (per-lane NaN-sentinel
// polls, 2 barriers, 4 staging waves, wave7 publisher, NREP=8 replicas) is
// untouched -- R7/R8/R9 all proved protocol restructures regress:
//   R7 pipelined/scalar polls +66us; R8 autonomous waves (8x poll traffic)
//   +478us; R9 counter gate (wait-all-64 + atomic hotspot + extra RT) +155us.
// Deltas:
//  1. __expf-based sigm/tanh (absmax-neutral, validated R7/R8/R9): shorter
//     serial nonlinearity chain.
//  2. Head: both 16B loads in ONE asm block, single vmcnt(0) -> 1 coherent
//     RT instead of 2 on wave6 (validated R9). Removes potential barrier1
//     gating on all group-0 blocks.
//  3. Wave7 publishes BEFORE barrier2 via LDS sentinel handoff: spins on
//     hout[8] (volatile), issues the 64-lane scatter store, resets hout,
//     then joins barrier2. Saves barrier-release + rescheduling latency on
//     the publish->visibility path. Both barriers kept; ordering of hout
//     reset vs next-step writes is provided by barrier2 + next barrier1.
// ---------------------------------------------------------------------------

#define TT    101
#define NBLK  256
#define NTH   512
#define NREP  8
#define SLAB_U32 512                               // 1024 f16 per replica
#define HB16_BYTES (4 * TT * NREP * SLAB_U32 * 4)  // 6,615,040 B
#define OUT_PROBS 6464
#define OUT_SAMP  6666
#define SENT 0xFFFFFFFFu

typedef _Float16 h2 __attribute__((ext_vector_type(2)));

__device__ __forceinline__ h2 mkh2(float a, float b) {
    h2 r; r.x = (_Float16)a; r.y = (_Float16)b; return r;
}
__device__ __forceinline__ unsigned pack2(float a, float b) {
    return __builtin_bit_cast(unsigned, mkh2(a, b));
}
__device__ __forceinline__ h2 as_h2(unsigned u) { return __builtin_bit_cast(h2, u); }

#if __has_builtin(__builtin_amdgcn_fdot2)
__device__ __forceinline__ float fdot2(h2 a, h2 b, float c) {
    return __builtin_amdgcn_fdot2(a, b, c, false);
}
#else
__device__ __forceinline__ float fdot2(h2 a, h2 b, float c) {
    return fmaf((float)a.x, (float)b.x, fmaf((float)a.y, (float)b.y, c));
}
#endif

// 16B cache-bypass load (coherent); waitcnt inside so result regs valid.
__device__ __forceinline__ uint4 load16_bypass(const uint4* p) {
    uint4 r;
    asm volatile("global_load_dwordx4 %0, %1, off sc0 sc1\n\ts_waitcnt vmcnt(0)"
                 : "=v"(r) : "v"(p) : "memory");
    return r;
}
__device__ __forceinline__ void store4_bypass(unsigned* p, unsigned v) {
    asm volatile("global_store_dword %0, %1, off sc0 sc1" :: "v"(p), "v"(v) : "memory");
}
// Two 16B cache-bypass loads back-to-back, ONE vmcnt(0): 1 RT not 2.
__device__ __forceinline__ void load32_bypass2(const uint4* p0, const uint4* p1,
                                               uint4& r0, uint4& r1) {
    asm volatile("global_load_dwordx4 %0, %2, off sc0 sc1\n\t"
                 "global_load_dwordx4 %1, %3, off sc0 sc1\n\t"
                 "s_waitcnt vmcnt(0)"
                 : "=&v"(r0), "=&v"(r1) : "v"(p0), "v"(p1) : "memory");
}
// R5's proven serial poll: load, check, sleep-retry.
__device__ __forceinline__ uint4 poll16(const uint4* p) {
    uint4 r = load16_bypass(p);
    while (r.x == SENT || r.y == SENT || r.z == SENT || r.w == SENT) {
        __builtin_amdgcn_s_sleep(1);
        r = load16_bypass(p);
    }
    return r;
}
__device__ __forceinline__ bool stale(const uint4& u) {
    return (u.x == SENT) | (u.y == SENT) | (u.z == SENT) | (u.w == SENT);
}

// rocPRIM-style full-wave (64) sum via DPP; total broadcast via readlane(63).
__device__ __forceinline__ float wave_sum(float x) {
    int v;
    v = __builtin_amdgcn_update_dpp(0, __builtin_bit_cast(int, x), 0x111, 0xf, 0xf, false);
    x += __builtin_bit_cast(float, v);                                  // row_shr:1
    v = __builtin_amdgcn_update_dpp(0, __builtin_bit_cast(int, x), 0x112, 0xf, 0xf, false);
    x += __builtin_bit_cast(float, v);                                  // row_shr:2
    v = __builtin_amdgcn_update_dpp(0, __builtin_bit_cast(int, x), 0x114, 0xf, 0xe, false);
    x += __builtin_bit_cast(float, v);                                  // row_shr:4
    v = __builtin_amdgcn_update_dpp(0, __builtin_bit_cast(int, x), 0x118, 0xf, 0xc, false);
    x += __builtin_bit_cast(float, v);                                  // row_shr:8
    v = __builtin_amdgcn_update_dpp(0, __builtin_bit_cast(int, x), 0x142, 0xa, 0xf, false);
    x += __builtin_bit_cast(float, v);                                  // row_bcast:15
    v = __builtin_amdgcn_update_dpp(0, __builtin_bit_cast(int, x), 0x143, 0xc, 0xf, false);
    x += __builtin_bit_cast(float, v);                                  // row_bcast:31
    return __builtin_bit_cast(float, __builtin_amdgcn_readlane(__builtin_bit_cast(int, x), 63));
}

// fast transcendentals (v_exp_f32-based); validated R7/R8/R9: absmax equal.
__device__ __forceinline__ float sigm(float x)   { return 1.f / (1.f + __expf(-x)); }
__device__ __forceinline__ float tanh_f(float x) { return 1.f - 2.f / (1.f + __expf(x + x)); }

// ---------------------------------------------------------------------------
__global__ __launch_bounds__(NTH, 2) void lstm_kernel(
    const float* __restrict__ z,
    const float* __restrict__ Wih, const float* __restrict__ Whh,
    const float* __restrict__ bih, const float* __restrict__ bhh,
    const float* __restrict__ Ws,  const float* __restrict__ bs,
    const float* __restrict__ Wp,  const float* __restrict__ bp,
    unsigned* __restrict__ hb16, float* __restrict__ out)
{
    const int tid  = threadIdx.x;
    const int wv   = tid >> 6;
    const int lane = tid & 63;
    const int l    = blockIdx.x >> 6;          // layer / group
    const int gb   = blockIdx.x & 63;          // block-in-group
    const int uA   = (gb << 4) + (wv << 1);    // wave's first unit

    __shared__ __align__(16) uint4 vh4[256];   // 256 chunks: [part1 128 | part2 128]
    __shared__ unsigned hout[8];               // packed h pair per wave (SENT-gated)

    // ---- weights -> registers (fp32 -> f16), chunk-aligned layout --------
    // lane's dot coverage: chunks {lane, 64+lane} of each part
    //   k0-3:  Whh cols 8*lane   .. +7      k4-7:  Whh cols 512+8*lane .. +7
    //   k8-11: Wih cols 8*lane   .. +7      k12-15:Wih cols 512+8*lane .. +7
    h2 w[8][16];
    #pragma unroll
    for (int r = 0; r < 8; ++r) {
        const int u = uA + (r >> 2);
        const int g = r & 3;
        const size_t row = ((size_t)((l << 12) + (g << 10) + u)) << 10;
        const float4* pa = (const float4*)(Whh + row + (lane << 3));
        const float4* pb = (const float4*)(Whh + row + 512 + (lane << 3));
        const float4* pc = (const float4*)(Wih + row + (lane << 3));
        const float4* pd = (const float4*)(Wih + row + 512 + (lane << 3));
        float4 f;
        f = pa[0]; w[r][0]  = mkh2(f.x, f.y); w[r][1]  = mkh2(f.z, f.w);
        f = pa[1]; w[r][2]  = mkh2(f.x, f.y); w[r][3]  = mkh2(f.z, f.w);
        f = pb[0]; w[r][4]  = mkh2(f.x, f.y); w[r][5]  = mkh2(f.z, f.w);
        f = pb[1]; w[r][6]  = mkh2(f.x, f.y); w[r][7]  = mkh2(f.z, f.w);
        f = pc[0]; w[r][8]  = mkh2(f.x, f.y); w[r][9]  = mkh2(f.z, f.w);
        f = pc[1]; w[r][10] = mkh2(f.x, f.y); w[r][11] = mkh2(f.z, f.w);
        f = pd[0]; w[r][12] = mkh2(f.x, f.y); w[r][13] = mkh2(f.z, f.w);
        f = pd[1]; w[r][14] = mkh2(f.x, f.y); w[r][15] = mkh2(f.z, f.w);
    }

    float bA[4], bB[4];
    #pragma unroll
    for (int g = 0; g < 4; ++g) {
        const int iA = (l << 12) + (g << 10) + uA;
        bA[g] = bih[iA] + bhh[iA];
        bB[g] = bih[iA + 1] + bhh[iA + 1];
    }

    // ---- head role (wave 6) ----------------------------------------------
    const bool role_states = (l == 0 && wv == 6);
    const bool role_probs  = (l == 1 && gb == 0 && wv == 6);
    float hw0[16], hw1[16], hb0 = 0.f, hb1 = 0.f;
    if (role_states) {
        #pragma unroll
        for (int k = 0; k < 16; ++k) hw0[k] = Ws[(gb << 10) + (lane << 4) + k];
        hb0 = bs[gb];
    } else if (role_probs) {
        #pragma unroll
        for (int k = 0; k < 16; ++k) {
            hw0[k] = Wp[(lane << 4) + k];
            hw1[k] = Wp[1024 + (lane << 4) + k];
        }
        hb0 = bp[0]; hb1 = bp[1];
    }
    int th = 0;

    float cstA = 0.f, cstB = 0.f;

    // hout sentinel init (ordered before first writes by barrier1 of t=0)
    if (tid < 8) hout[tid] = SENT;

    #pragma unroll 1
    for (int t = 0; t < TT; ++t) {
        const bool full = (l > 0) || (t == 0);
        const int rep = (gb + wv) & (NREP - 1);

        // ---- staging (waves 0-3; they never global-store) ----
        if (wv < 2) {                              // part1: h_l(t-1)
            const int c = (wv << 6) + lane;
            if (t == 0) vh4[c] = make_uint4(0, 0, 0, 0);
            else {
                const uint4* slab = (const uint4*)(hb16 + (size_t)((l * TT + t - 1) * NREP + rep) * SLAB_U32);
                vh4[c] = poll16(slab + c);
            }
        } else if (wv < 4) {                       // part2: h_{l-1}(t) or z
            const int c = ((wv - 2) << 6) + lane;
            if (l > 0) {
                const uint4* slab = (const uint4*)(hb16 + (size_t)(((l - 1) * TT + t) * NREP + rep) * SLAB_U32);
                vh4[128 + c] = poll16(slab + c);
            } else if (t == 0) {
                const float4 f0 = *(const float4*)(z + (c << 3));
                const float4 f1 = *(const float4*)(z + (c << 3) + 4);
                vh4[128 + c] = make_uint4(pack2(f0.x, f0.y), pack2(f0.z, f0.w),
                                          pack2(f1.x, f1.y), pack2(f1.z, f1.w));
            }
        }
        __syncthreads();                           // barrier1

        // ---- dot: 8 gate rows per wave, 4x ds_read_b128 ----
        float acc[8] = {0.f, 0.f, 0.f, 0.f, 0.f, 0.f, 0.f, 0.f};
        {
            const uint4 A1 = vh4[lane];
            const uint4 A2 = vh4[64 + lane];
            const unsigned a8[8] = {A1.x, A1.y, A1.z, A1.w, A2.x, A2.y, A2.z, A2.w};
            #pragma unroll
            for (int k = 0; k < 8; ++k) {
                const h2 v2 = as_h2(a8[k]);
                #pragma unroll
                for (int r = 0; r < 8; ++r) acc[r] = fdot2(w[r][k], v2, acc[r]);
            }
            if (full) {
                const uint4 B1 = vh4[128 + lane];
                const uint4 B2 = vh4[192 + lane];
                const unsigned b8[8] = {B1.x, B1.y, B1.z, B1.w, B2.x, B2.y, B2.z, B2.w};
                #pragma unroll
                for (int k = 0; k < 8; ++k) {
                    const h2 v2 = as_h2(b8[k]);
                    #pragma unroll
                    for (int r = 0; r < 8; ++r) acc[r] = fdot2(w[r][8 + k], v2, acc[r]);
                }
            }
        }

        // ---- DPP reduce (VALU pipe) -> uniform gate sums ----
        float tot[8];
        #pragma unroll
        for (int r = 0; r < 8; ++r) tot[r] = wave_sum(acc[r]);

        // ---- uniform nonlinearity on all lanes ----
        cstA = fmaf(sigm(tot[1] + bA[1]), cstA, sigm(tot[0] + bA[0]) * tanh_f(tot[2] + bA[2]));
        cstB = fmaf(sigm(tot[5] + bB[1]), cstB, sigm(tot[4] + bB[0]) * tanh_f(tot[6] + bB[2]));
        const float hA = sigm(tot[3] + bA[3]) * tanh_f(cstA);
        const float hB = sigm(tot[7] + bB[3]) * tanh_f(cstB);
        if (lane == 0) ((volatile unsigned*)hout)[wv] = pack2(hA, hB);

        if (wv == 7) {
            // ---- publish BEFORE barrier2: spin on hout (LDS, fast), issue
            // the 64-lane scatter store immediately, reset hout, then join
            // barrier2. Store-ack drains lazily (next iteration's staging
            // polls don't wait on it; waves 0-3 never global-store).
            volatile unsigned* vho = (volatile unsigned*)hout;
            unsigned v = vho[lane & 7];
            while (v == SENT) { v = vho[lane & 7]; }
            unsigned* addr = hb16 + (size_t)(l * TT + t) * NREP * SLAB_U32
                           + (size_t)(lane >> 3) * SLAB_U32 + (gb << 3) + (lane & 7);
            store4_bypass(addr, v);
            if (lane < 8) vho[lane] = SENT;        // reset for t+1 (ordered by b2+b1)
        } else if ((role_states || role_probs) && th < TT && th <= t - 3) {
            // ---- head: non-blocking single-shot try at lag 3 (1 fused RT) ----
            const int hrep = (gb + th) & (NREP - 1);
            const uint4* slab3 = (const uint4*)(hb16 + (size_t)((3 * TT + th) * NREP + hrep) * SLAB_U32);
            uint4 r0, r1;
            load32_bypass2(slab3 + (lane << 1), slab3 + (lane << 1) + 1, r0, r1);
            const bool ok = !(stale(r0) | stale(r1));
            if (__ballot(ok) == ~0ull) {
                const unsigned u8[8] = {r0.x, r0.y, r0.z, r0.w, r1.x, r1.y, r1.z, r1.w};
                if (role_states) {
                    float a = 0.f;
                    #pragma unroll
                    for (int j = 0; j < 8; ++j) {
                        const h2 p = as_h2(u8[j]);
                        a = fmaf(hw0[2 * j], (float)p.x, a);
                        a = fmaf(hw0[2 * j + 1], (float)p.y, a);
                    }
                    const float tots = wave_sum(a);
                    if (lane == 0) out[th * 64 + gb] = tots + hb0;
                } else {
                    float a0 = 0.f, a1 = 0.f;
                    #pragma unroll
                    for (int j = 0; j < 8; ++j) {
                        const h2 p = as_h2(u8[j]);
                        a0 = fmaf(hw0[2 * j], (float)p.x, a0); a0 = fmaf(hw0[2 * j + 1], (float)p.y, a0);
                        a1 = fmaf(hw1[2 * j], (float)p.x, a1); a1 = fmaf(hw1[2 * j + 1], (float)p.y, a1);
                    }
                    const float t0 = wave_sum(a0), t1 = wave_sum(a1);
                    if (lane == 0) {
                        float p0, p1;
                        if (th == TT - 1) { p0 = 0.f; p1 = 1.f; }
                        else {
                            const float l0 = t0 + hb0 + 1.0f;   // P_BIAS
                            const float l1 = t1 + hb1;
                            const float m  = fmaxf(l0, l1);
                            const float e0 = expf(l0 - m), e1 = expf(l1 - m);
                            const float inv = 1.f / (e0 + e1);
                            p0 = e0 * inv; p1 = e1 * inv;
                        }
                        out[OUT_PROBS + 2 * th]     = p0;
                        out[OUT_PROBS + 2 * th + 1] = p1;
                        out[OUT_SAMP + th] = (th == TT - 1) ? 1.0f : 0.0f;
                    }
                }
                ++th;
            }
        }
        __syncthreads();                           // barrier2
    }

    // ---- head drain (blocking) ----
    if (role_states || role_probs) {
        while (th < TT) {
            const int hrep = (gb + th) & (NREP - 1);
            const uint4* slab3 = (const uint4*)(hb16 + (size_t)((3 * TT + th) * NREP + hrep) * SLAB_U32);
            uint4 r0, r1;
            for (;;) {
                load32_bypass2(slab3 + (lane << 1), slab3 + (lane << 1) + 1, r0, r1);
                if (!(stale(r0) | stale(r1))) break;
                __builtin_amdgcn_s_sleep(1);
            }
            const unsigned u8[8] = {r0.x, r0.y, r0.z, r0.w, r1.x, r1.y, r1.z, r1.w};
            if (role_states) {
                float a = 0.f;
                #pragma unroll
                for (int j = 0; j < 8; ++j) {
                    const h2 p = as_h2(u8[j]);
                    a = fmaf(hw0[2 * j], (float)p.x, a);
                    a = fmaf(hw0[2 * j + 1], (float)p.y, a);
                }
                const float tots = wave_sum(a);
                if (lane == 0) out[th * 64 + gb] = tots + hb0;
            } else {
                float a0 = 0.f, a1 = 0.f;
                #pragma unroll
                for (int j = 0; j < 8; ++j) {
                    const h2 p = as_h2(u8[j]);
                    a0 = fmaf(hw0[2 * j], (float)p.x, a0); a0 = fmaf(hw0[2 * j + 1], (float)p.y, a0);
                    a1 = fmaf(hw1[2 * j], (float)p.x, a1); a1 = fmaf(hw1[2 * j + 1], (float)p.y, a1);
                }
                const float t0 = wave_sum(a0), t1 = wave_sum(a1);
                if (lane == 0) {
                    float p0, p1;
                    if (th == TT - 1) { p0 = 0.f; p1 = 1.f; }
                    else {
                        const float l0 = t0 + hb0 + 1.0f;
                        const float l1 = t1 + hb1;
                        const float m  = fmaxf(l0, l1);
                        const float e0 = expf(l0 - m), e1 = expf(l1 - m);
                        const float inv = 1.f / (e0 + e1);
                        p0 = e0 * inv; p1 = e1 * inv;
                    }
                    out[OUT_PROBS + 2 * th]     = p0;
                    out[OUT_PROBS + 2 * th + 1] = p1;
                    out[OUT_SAMP + th] = (th == TT - 1) ? 1.0f : 0.0f;
                }
            }
            ++th;
        }
    }
}

// ---------------------------------------------------------------------------
extern "C" void kernel_launch(void* const* d_in, const int* in_sizes, int n_in,
                              void* d_out, int out_size, void* d_ws, size_t ws_size,
                              hipStream_t stream)
{
    const float* z   = (const float*)d_in[0];
    const float* Wih = (const float*)d_in[1];
    const float* Whh = (const float*)d_in[2];
    const float* bih = (const float*)d_in[3];
    const float* bhh = (const float*)d_in[4];
    const float* Ws  = (const float*)d_in[5];
    const float* bs  = (const float*)d_in[6];
    const float* Wp  = (const float*)d_in[7];
    const float* bp  = (const float*)d_in[8];
    float* out = (float*)d_out;

    unsigned* hb16 = (unsigned*)d_ws;

    // sentinel-init replicas (ws is re-poisoned before every timed call)
    hipMemsetAsync(hb16, 0xFF, HB16_BYTES, stream);
    lstm_kernel<<<NBLK, NTH, 0, stream>>>(z, Wih, Whh, bih, bhh,
                                          Ws, bs, Wp, bp, hb16, out);
}